// Round 1
// baseline (239.587 us; speedup 1.0000x reference)
//
#include <hip/hip_runtime.h>
#include <hip/hip_bf16.h>
#include <stdint.h>

// LNLinearSigmoid: LayerNorm(x) @ W^T -> sigmoid
// x: [16384][2048] f32, W: [2048][2048] f32 (torch Linear layout [out,in])
// out: [16384][2048] f32
//
// Strategy: LN in fp32 -> bf16 xn (ws), W -> bf16 (ws), then 128x128-tile
// bf16 MFMA GEMM (m97 structure: BK=64, global_load_lds width 16, 4 waves,
// 4x4 acc of 16x16x32 fragments) with sigmoid epilogue.
// Workspace requirement: 16384*2048*2 + 2048*2048*2 = 75.5 MB.

typedef __attribute__((ext_vector_type(4))) float f32x4;
typedef __attribute__((ext_vector_type(8))) __bf16 b16x8;

__device__ __forceinline__ void async16(void* lds, const void* g) {
  __builtin_amdgcn_global_load_lds(
      (const __attribute__((address_space(1))) void*)g,
      (__attribute__((address_space(3))) void*)lds, 16, 0, 0);
}

__device__ __forceinline__ unsigned short f2bf(float f) {
  uint32_t u = __float_as_uint(f);
  u += 0x7FFFu + ((u >> 16) & 1u);   // round-to-nearest-even
  return (unsigned short)(u >> 16);
}

// ---------------- LayerNorm: one block per row, fp32 in, bf16 out ----------
__global__ __launch_bounds__(256) void ln_bf16_kernel(
    const float* __restrict__ x, unsigned short* __restrict__ xn) {
  const int row = blockIdx.x;
  const int t = threadIdx.x;            // 0..255
  const float4* xr = (const float4*)(x + (size_t)row * 2048);
  float4 a = xr[t];
  float4 b = xr[t + 256];
  float s = a.x + a.y + a.z + a.w + b.x + b.y + b.z + b.w;
  float q = a.x * a.x + a.y * a.y + a.z * a.z + a.w * a.w +
            b.x * b.x + b.y * b.y + b.z * b.z + b.w * b.w;
#pragma unroll
  for (int off = 32; off > 0; off >>= 1) {
    s += __shfl_down(s, off);
    q += __shfl_down(q, off);
  }
  __shared__ float red[8];
  const int w = t >> 6;
  if ((t & 63) == 0) { red[w] = s; red[4 + w] = q; }
  __syncthreads();
  s = red[0] + red[1] + red[2] + red[3];
  q = red[4] + red[5] + red[6] + red[7];
  const float mean = s * (1.0f / 2048.0f);
  const float var = fmaxf(q * (1.0f / 2048.0f) - mean * mean, 0.0f);
  const float scl = rsqrtf(var + 1e-5f);
  ushort4 o0, o1;
  o0.x = f2bf((a.x - mean) * scl);
  o0.y = f2bf((a.y - mean) * scl);
  o0.z = f2bf((a.z - mean) * scl);
  o0.w = f2bf((a.w - mean) * scl);
  o1.x = f2bf((b.x - mean) * scl);
  o1.y = f2bf((b.y - mean) * scl);
  o1.z = f2bf((b.z - mean) * scl);
  o1.w = f2bf((b.w - mean) * scl);
  ushort4* orow = (ushort4*)(xn + (size_t)row * 2048);
  orow[t] = o0;
  orow[t + 256] = o1;
}

// ---------------- W fp32 -> bf16 ------------------------------------------
__global__ __launch_bounds__(256) void wconv_kernel(
    const float* __restrict__ W, unsigned short* __restrict__ Wb) {
  const size_t i = (size_t)blockIdx.x * 256 + threadIdx.x;  // float4 index
  float4 v = ((const float4*)W)[i];
  ushort4 o;
  o.x = f2bf(v.x);
  o.y = f2bf(v.y);
  o.z = f2bf(v.z);
  o.w = f2bf(v.w);
  ((ushort4*)Wb)[i] = o;
}

// ---------------- GEMM: C = A(bf16) * B^T(bf16) + sigmoid, fp32 out -------
// A: [16384][2048] bf16 row-major (xn), B: [2048][2048] bf16 row-major [N][K]
// Tile BM=BN=128, BK=64. 4 waves (2x2), each computes 64x64 via 4x4 frags of
// v_mfma_f32_16x16x32_bf16. Staging via global_load_lds width 16, linear LDS.
__global__ __launch_bounds__(256) void gemm_bt_sig(
    const unsigned short* __restrict__ A, const unsigned short* __restrict__ B,
    float* __restrict__ C) {
  __shared__ __align__(16) unsigned short sA[128 * 64];
  __shared__ __align__(16) unsigned short sB[128 * 64];

  const int bid = blockIdx.x;
  const int bm = bid >> 4;   // 128 row-tiles
  const int bn = bid & 15;   // 16 col-tiles
  const int tid = threadIdx.x;
  const int w = tid >> 6;          // wave 0..3
  const int l = tid & 63;          // lane
  const int wr = w >> 1, wc = w & 1;
  const int lr8 = l >> 3;          // row within 8-row staging chunk
  const int lc8 = (l & 7) * 8;     // bf16-col within 64-wide K slab
  const int fr = l & 15;           // fragment row (A: m, B: n)
  const int fg = l >> 4;           // k-group 0..3

  const unsigned short* gA = A + (size_t)(bm * 128) * 2048;
  const unsigned short* gB = B + (size_t)(bn * 128) * 2048;

  f32x4 acc[4][4] = {};

  for (int kt = 0; kt < 2048; kt += 64) {
    // stage: each wave writes 4 contiguous 1KB chunks for A and B
#pragma unroll
    for (int c = 0; c < 4; ++c) {
      const int row = (c * 4 + w) * 8 + lr8;
      async16(&sA[row * 64 + lc8], gA + (size_t)row * 2048 + kt + lc8);
      async16(&sB[row * 64 + lc8], gB + (size_t)row * 2048 + kt + lc8);
    }
    __syncthreads();   // drains vmcnt(0): staged data visible

#pragma unroll
    for (int s = 0; s < 2; ++s) {  // two K=32 sub-steps
      b16x8 af[4], bfr[4];
#pragma unroll
      for (int i = 0; i < 4; ++i)
        af[i] = *(const b16x8*)&sA[(wr * 64 + i * 16 + fr) * 64 + s * 32 + fg * 8];
#pragma unroll
      for (int j = 0; j < 4; ++j)
        bfr[j] = *(const b16x8*)&sB[(wc * 64 + j * 16 + fr) * 64 + s * 32 + fg * 8];
#pragma unroll
      for (int i = 0; i < 4; ++i)
#pragma unroll
        for (int j = 0; j < 4; ++j)
          acc[i][j] = __builtin_amdgcn_mfma_f32_16x16x32_bf16(
              af[i], bfr[j], acc[i][j], 0, 0, 0);
    }
    __syncthreads();   // protect LDS before next stage overwrites
  }

  // epilogue: sigmoid, fp32 store. C/D layout: col=lane&15, row=(lane>>4)*4+r
  float* gC = C + (size_t)(bm * 128 + wr * 64) * 2048 + bn * 128 + wc * 64;
#pragma unroll
  for (int i = 0; i < 4; ++i) {
#pragma unroll
    for (int j = 0; j < 4; ++j) {
#pragma unroll
      for (int r = 0; r < 4; ++r) {
        const int row = i * 16 + fg * 4 + r;
        const int col = j * 16 + fr;
        const float y = acc[i][j][r];
        gC[(size_t)row * 2048 + col] = 1.0f / (1.0f + __expf(-y));
      }
    }
  }
}

extern "C" void kernel_launch(void* const* d_in, const int* in_sizes, int n_in,
                              void* d_out, int out_size, void* d_ws, size_t ws_size,
                              hipStream_t stream) {
  const float* x = (const float*)d_in[0];   // [16384][2048]
  const float* W = (const float*)d_in[1];   // [2048][2048]
  float* out = (float*)d_out;               // [16384][2048]

  unsigned short* xnb = (unsigned short*)d_ws;                       // 67 MB
  unsigned short* Wb =
      (unsigned short*)((char*)d_ws + (size_t)16384 * 2048 * 2);     // 8.4 MB

  ln_bf16_kernel<<<16384, 256, 0, stream>>>(x, xnb);
  wconv_kernel<<<(2048 * 2048 / 4) / 256, 256, 0, stream>>>(W, Wb);
  gemm_bt_sig<<<128 * 16, 256, 0, stream>>>(xnb, Wb, out);
}

// Round 2
// 169.879 us; speedup vs baseline: 1.4103x; 1.4103x over previous
//
#include <hip/hip_runtime.h>
#include <hip/hip_bf16.h>
#include <stdint.h>

// LNLinearSigmoid: LayerNorm(x) @ W^T -> sigmoid
// x: [16384][2048] f32, W: [2048][2048] f32 -> out [16384][2048] f32
// Pipeline: LN->bf16 (ws), W->bf16 (ws), then 256x256-tile 8-phase bf16 MFMA
// GEMM (T1 XCD swizzle + T2 LDS XOR swizzle + T3/T4 counted vmcnt + T5
// setprio), sigmoid epilogue. ws >= 75.5 MB.

typedef __attribute__((ext_vector_type(4))) float f32x4;
typedef __attribute__((ext_vector_type(8))) __bf16 b16x8;

__device__ __forceinline__ void async16(void* lds, const void* g) {
  __builtin_amdgcn_global_load_lds(
      (const __attribute__((address_space(1))) void*)g,
      (__attribute__((address_space(3))) void*)lds, 16, 0, 0);
}

__device__ __forceinline__ unsigned short f2bf(float f) {
  uint32_t u = __float_as_uint(f);
  u += 0x7FFFu + ((u >> 16) & 1u);
  return (unsigned short)(u >> 16);
}

// ---------------- LayerNorm: one block per row, fp32 in, bf16 out ----------
__global__ __launch_bounds__(256) void ln_bf16_kernel(
    const float* __restrict__ x, unsigned short* __restrict__ xn) {
  const int row = blockIdx.x;
  const int t = threadIdx.x;
  const float4* xr = (const float4*)(x + (size_t)row * 2048);
  float4 a = xr[t];
  float4 b = xr[t + 256];
  float s = a.x + a.y + a.z + a.w + b.x + b.y + b.z + b.w;
  float q = a.x * a.x + a.y * a.y + a.z * a.z + a.w * a.w +
            b.x * b.x + b.y * b.y + b.z * b.z + b.w * b.w;
#pragma unroll
  for (int off = 32; off > 0; off >>= 1) {
    s += __shfl_down(s, off);
    q += __shfl_down(q, off);
  }
  __shared__ float red[8];
  const int w = t >> 6;
  if ((t & 63) == 0) { red[w] = s; red[4 + w] = q; }
  __syncthreads();
  s = red[0] + red[1] + red[2] + red[3];
  q = red[4] + red[5] + red[6] + red[7];
  const float mean = s * (1.0f / 2048.0f);
  const float var = fmaxf(q * (1.0f / 2048.0f) - mean * mean, 0.0f);
  const float scl = rsqrtf(var + 1e-5f);
  ushort4 o0, o1;
  o0.x = f2bf((a.x - mean) * scl);
  o0.y = f2bf((a.y - mean) * scl);
  o0.z = f2bf((a.z - mean) * scl);
  o0.w = f2bf((a.w - mean) * scl);
  o1.x = f2bf((b.x - mean) * scl);
  o1.y = f2bf((b.y - mean) * scl);
  o1.z = f2bf((b.z - mean) * scl);
  o1.w = f2bf((b.w - mean) * scl);
  ushort4* orow = (ushort4*)(xn + (size_t)row * 2048);
  orow[t] = o0;
  orow[t + 256] = o1;
}

// ---------------- W fp32 -> bf16 ------------------------------------------
__global__ __launch_bounds__(256) void wconv_kernel(
    const float* __restrict__ W, unsigned short* __restrict__ Wb) {
  const size_t i = (size_t)blockIdx.x * 256 + threadIdx.x;
  float4 v = ((const float4*)W)[i];
  ushort4 o;
  o.x = f2bf(v.x);
  o.y = f2bf(v.y);
  o.z = f2bf(v.z);
  o.w = f2bf(v.w);
  ((ushort4*)Wb)[i] = o;
}

// ---------------- 256x256 8-phase GEMM ------------------------------------
// A: [16384][2048] bf16, B: [2048][2048] bf16 ([N][K]), C fp32 + sigmoid.
// BM=BN=256, BK=64, 8 waves (2Mx4N), 512 threads. LDS 128KB:
//   regions (16KB each): buf*65536 + {A0:0, A1:16K, B0:32K, B1:48K}
// Wave ownership interleaved: rows = qm*128 + wr*64 + i*16 + fr (i=0..3)
//                             cols = qn*128 + wc*32 + j*16 + fr (j=0..1)
// Phase order per K-tile: (qm,qn) = (0,0),(0,1),(1,1),(1,0) -> each phase
// newly reads ONE half-tile. Stages: P1:A1(t1); P2..P5:B0,A0,B1,A1(t2);
// P6..P8:B0,A0,B1(t3). vmcnt(6) at P4/P8 => 3 half-tiles in flight.
// LDS swizzle: 16B-slot XOR (row&7) on BOTH source addr and ds_read addr.

#define STG_A(buf, h, kt)                                              \
  do {                                                                 \
    const char* s_ = pA + (size_t)((h) * 128) * 4096 + (kt) * 128;     \
    char* d_ = lds + (buf) * 65536 + (h) * 16384 + tid * 16;           \
    async16(d_, s_);                                                   \
    async16(d_ + 8192, s_ + 64 * 4096);                                \
  } while (0)

#define STG_B(buf, h, kt)                                              \
  do {                                                                 \
    const char* s_ = pB + (size_t)((h) * 128) * 4096 + (kt) * 128;     \
    char* d_ = lds + 32768 + (buf) * 65536 + (h) * 16384 + tid * 16;   \
    async16(d_, s_);                                                   \
    async16(d_ + 8192, s_ + 64 * 4096);                                \
  } while (0)

#define LDA(buf, qm)                                                   \
  do {                                                                 \
    _Pragma("unroll") for (int i_ = 0; i_ < 4; ++i_) {                 \
      const char* p_ = lds + (buf) * 65536 + (qm) * 16384 + abase + i_ * 2048; \
      aF[i_][0] = *(const b16x8*)(p_ + cs0);                           \
      aF[i_][1] = *(const b16x8*)(p_ + cs1);                           \
    }                                                                  \
  } while (0)

#define LDB(dstf, buf, qn)                                             \
  do {                                                                 \
    _Pragma("unroll") for (int j_ = 0; j_ < 2; ++j_) {                 \
      const char* p_ = lds + (buf) * 65536 + (qn) * 16384 + bbase + j_ * 2048; \
      dstf[j_][0] = *(const b16x8*)(p_ + cs0);                         \
      dstf[j_][1] = *(const b16x8*)(p_ + cs1);                         \
    }                                                                  \
  } while (0)

#define MFMA_Q(qm, qn, BF)                                             \
  do {                                                                 \
    __builtin_amdgcn_s_setprio(1);                                     \
    _Pragma("unroll") for (int i_ = 0; i_ < 4; ++i_) {                 \
      _Pragma("unroll") for (int j_ = 0; j_ < 2; ++j_) {               \
        f32x4 c_ = acc[(qm) * 4 + i_][(qn) * 2 + j_];                  \
        c_ = __builtin_amdgcn_mfma_f32_16x16x32_bf16(aF[i_][0], BF[j_][0], c_, 0, 0, 0); \
        c_ = __builtin_amdgcn_mfma_f32_16x16x32_bf16(aF[i_][1], BF[j_][1], c_, 0, 0, 0); \
        acc[(qm) * 4 + i_][(qn) * 2 + j_] = c_;                        \
      }                                                                \
    }                                                                  \
    __builtin_amdgcn_s_setprio(0);                                     \
  } while (0)

#define BAR1                                                           \
  do {                                                                 \
    __builtin_amdgcn_s_barrier();                                      \
    asm volatile("s_waitcnt lgkmcnt(0)" ::: "memory");                 \
    __builtin_amdgcn_sched_barrier(0);                                 \
  } while (0)

#define BAR2                                                           \
  do {                                                                 \
    __builtin_amdgcn_s_barrier();                                      \
    asm volatile("" ::: "memory");                                     \
  } while (0)

#define VMC(n) asm volatile("s_waitcnt vmcnt(" #n ")" ::: "memory")

__global__ __launch_bounds__(512, 2) void gemm8p(
    const unsigned short* __restrict__ A, const unsigned short* __restrict__ B,
    float* __restrict__ C) {
  __shared__ __align__(16) char lds[131072];

  const int bid0 = blockIdx.x;                       // 512 blocks
  const int bid = (bid0 & 7) * 64 + (bid0 >> 3);     // XCD swizzle (512%8==0)
  const int bm = bid >> 3;                           // 0..63
  const int bn = bid & 7;                            // 0..7

  const int tid = threadIdx.x;
  const int w = tid >> 6, l = tid & 63;
  const int wr = w >> 2, wc = w & 3;
  const int fr = l & 15, fg = l >> 4;

  // staging source addrs (linear LDS dest, inverse-swizzled global source)
  const int arow = tid >> 3;                              // 0..63
  const int swz = ((tid & 7) << 4) ^ ((arow & 7) << 4);   // within-row 16B slot
  const char* pA = (const char*)A + (size_t)(bm * 256 + arow) * 4096 + swz;
  const char* pB = (const char*)B + (size_t)(bn * 256 + arow) * 4096 + swz;

  // ds_read offsets (swizzled)
  const int cswz = (fg << 4) ^ ((fr & 7) << 4);
  const int cs0 = cswz, cs1 = cswz ^ 64;
  const int abase = (wr * 64 + fr) * 128;
  const int bbase = 32768 + (wc * 32 + fr) * 128;

  f32x4 acc[8][4] = {};
  b16x8 aF[4][2], b0F[2][2], b1F[2][2];

  // prologue: t0 fully (buf0), then B0,A0,B1 of t1 (buf1) in that order
  STG_A(0, 0, 0); STG_B(0, 0, 0); STG_B(0, 1, 0); STG_A(0, 1, 0);
  STG_B(1, 0, 1); STG_A(1, 0, 1); STG_B(1, 1, 1);
  VMC(6);
  __builtin_amdgcn_s_barrier();
  asm volatile("" ::: "memory");

#pragma unroll 1
  for (int it = 0; it < 16; ++it) {
    const int t1 = 2 * it + 1, t2 = 2 * it + 2, t3 = 2 * it + 3;
    const bool s2 = (t2 < 32), s3 = (t3 < 32);

    // P1: (0,0) buf0; stage A1(t1)->buf1.A1
    LDA(0, 0); LDB(b0F, 0, 0);
    STG_A(1, 1, t1);
    BAR1; MFMA_Q(0, 0, b0F); BAR2;

    // P2: (0,1) buf0; stage B0(t2)->buf0.B0
    LDB(b1F, 0, 1);
    if (s2) STG_B(0, 0, t2);
    BAR1; MFMA_Q(0, 1, b1F); BAR2;

    // P3: (1,1) buf0; stage A0(t2)->buf0.A0
    LDA(0, 1);
    if (s2) STG_A(0, 0, t2);
    BAR1; MFMA_Q(1, 1, b1F); BAR2;

    // P4: (1,0) buf0; stage B1(t2)->buf0.B1; vmcnt
    if (s2) STG_B(0, 1, t2);
    BAR1; MFMA_Q(1, 0, b0F);
    if (it < 15) { VMC(6); } else { VMC(0); }
    BAR2;

    // P5: (0,0) buf1; stage A1(t2)->buf0.A1
    LDA(1, 0); LDB(b0F, 1, 0);
    if (s2) STG_A(0, 1, t2);
    BAR1; MFMA_Q(0, 0, b0F); BAR2;

    // P6: (0,1) buf1; stage B0(t3)->buf1.B0
    LDB(b1F, 1, 1);
    if (s3) STG_B(1, 0, t3);
    BAR1; MFMA_Q(0, 1, b1F); BAR2;

    // P7: (1,1) buf1; stage A0(t3)->buf1.A0
    LDA(1, 1);
    if (s3) STG_A(1, 0, t3);
    BAR1; MFMA_Q(1, 1, b1F); BAR2;

    // P8: (1,0) buf1; stage B1(t3)->buf1.B1; vmcnt
    if (s3) STG_B(1, 1, t3);
    BAR1; MFMA_Q(1, 0, b0F);
    if (it < 15) { VMC(6); }
    BAR2;
  }

  // epilogue: sigmoid + store. C/D frag: row=fg*4+r, col=fr.
  float* gC = C + (size_t)(bm * 256) * 2048 + bn * 256;
#pragma unroll
  for (int qm = 0; qm < 2; ++qm) {
#pragma unroll
    for (int i = 0; i < 4; ++i) {
#pragma unroll
      for (int qn = 0; qn < 2; ++qn) {
#pragma unroll
        for (int j = 0; j < 2; ++j) {
#pragma unroll
          for (int r = 0; r < 4; ++r) {
            const int row = qm * 128 + wr * 64 + i * 16 + fg * 4 + r;
            const int col = qn * 128 + wc * 32 + j * 16 + fr;
            const float y = acc[qm * 4 + i][qn * 2 + j][r];
            gC[(size_t)row * 2048 + col] = 1.0f / (1.0f + __expf(-y));
          }
        }
      }
    }
  }
}

extern "C" void kernel_launch(void* const* d_in, const int* in_sizes, int n_in,
                              void* d_out, int out_size, void* d_ws, size_t ws_size,
                              hipStream_t stream) {
  const float* x = (const float*)d_in[0];
  const float* W = (const float*)d_in[1];
  float* out = (float*)d_out;

  unsigned short* xnb = (unsigned short*)d_ws;
  unsigned short* Wb =
      (unsigned short*)((char*)d_ws + (size_t)16384 * 2048 * 2);

  ln_bf16_kernel<<<16384, 256, 0, stream>>>(x, xnb);
  wconv_kernel<<<(2048 * 2048 / 4) / 256, 256, 0, stream>>>(W, Wb);
  gemm8p<<<512, 512, 0, stream>>>(xnb, Wb, out);
}